// Round 1
// baseline (178.612 us; speedup 1.0000x reference)
//
#include <hip/hip_runtime.h>
#include <hip/hip_bf16.h>

// GAT layer, N=8192, F_IN=256, F_OUT=64.
// Pipeline:
//  k1 : Wh = h@W -> packed bf16 B-fragments (Bpack); f = Wh@a[:64]; g = Wh@a[64:]
//  k2 : U = adj@Wh via MFMA (adj streamed once, 256MB); emits adj bitmask (8MB)
//       and per-row masked max of g (Gmax) as side products. Block = 16 rows,
//       8 waves split the j range, LDS reduce.
//  k2b: U f32 -> Upack bf16 in B-fragment layout.
//  k3 : single fused pass: weights w_ij = exp(leaky(f_i+g_j) - m_i) for edges
//       (m_i = leaky(f_i+Gmax_i)), MFMA P@Upack, denominator accumulated
//       alongside, block LDS reduce, divide + ELU, store.
//
// Fragment/packing conventions (self-consistent; HW facts used:
//  A row = lane&15, B col = lane&15, C/D col=lane&15 row=(lane>>4)*4+reg):
//  packed B layout: Bpack[(kb*4 + b)*64 + lane][e] = B[kb*32 + (lane>>4)*8 + e][b*16 + (lane&15)]
//  mask word: Mw[(rowblk*256 + jb)*8 + e] bit l = adj[rowblk*16 + (l&15)][jb*32 + (l>>4)*8 + e] > 0

#define N 8192
#define FIN 256
#define FOUT 64

typedef float f32x4 __attribute__((ext_vector_type(4)));
typedef short s16x8 __attribute__((ext_vector_type(8)));
typedef unsigned long long u64x2 __attribute__((ext_vector_type(2)));

__device__ __forceinline__ unsigned short f2bf(float x) {
  unsigned u = __float_as_uint(x);
  u += 0x7FFFu + ((u >> 16) & 1u);   // RNE
  return (unsigned short)(u >> 16);
}

// ---------------- k1: Wh, f, g, Bpack ----------------
__global__ __launch_bounds__(256) void k1(const float* __restrict__ h,
                                          const float* __restrict__ W,
                                          const float* __restrict__ a,
                                          unsigned short* __restrict__ Bpack,
                                          float* __restrict__ f,
                                          float* __restrict__ g) {
  const int lane = threadIdx.x & 63;
  const int w = threadIdx.x >> 6;
  const int i = blockIdx.x * 4 + w;        // row
  const float* hrow = h + (size_t)i * FIN;
  float acc = 0.f;
#pragma unroll 8
  for (int k = 0; k < FIN; ++k) {
    acc += hrow[k] * W[k * FOUT + lane];
  }
  float s1 = acc * a[lane];
  float s2 = acc * a[FOUT + lane];
#pragma unroll
  for (int d = 32; d > 0; d >>= 1) {
    s1 += __shfl_xor(s1, d);
    s2 += __shfl_xor(s2, d);
  }
  if (lane == 0) { f[i] = s1; g[i] = s2; }
  // Bpack element (k=i, n=lane)
  const int kb = i >> 5;
  const int b = lane >> 4;
  const int lp = (lane & 15) | (((i >> 3) & 3) << 4);
  const int e = i & 7;
  Bpack[(((size_t)(kb * 4 + b)) * 64 + lp) * 8 + e] = f2bf(acc);
}

// ---------------- k2: U = adj@Wh (MFMA) + mask + Gmax ----------------
__global__ __launch_bounds__(512, 4) void k2(const float* __restrict__ adj,
                                             const unsigned short* __restrict__ Bpack,
                                             const float* __restrict__ g,
                                             float* __restrict__ U,
                                             unsigned long long* __restrict__ Mw,
                                             float* __restrict__ Gmax) {
  __shared__ float red[8][64][16];   // 32 KB
  __shared__ float gred[8][16];
  const int lane = threadIdx.x & 63;
  const int w = threadIdx.x >> 6;
  const int i0 = blockIdx.x << 4;
  const int cgrp = (lane >> 4) << 3;
  const float* aprow = adj + (size_t)(i0 + (lane & 15)) * (size_t)N + cgrp;
  const s16x8* Bv = (const s16x8*)Bpack;
  f32x4 acc0 = {0.f, 0.f, 0.f, 0.f};
  f32x4 acc1 = {0.f, 0.f, 0.f, 0.f};
  f32x4 acc2 = {0.f, 0.f, 0.f, 0.f};
  f32x4 acc3 = {0.f, 0.f, 0.f, 0.f};
  float gmx = -INFINITY;
#pragma unroll 2
  for (int t = 0; t < 32; ++t) {
    const int jb = w + (t << 3);           // 0..255 across the 8 waves
    const int j0 = jb << 5;
    f32x4 a0 = *(const f32x4*)(aprow + j0);
    f32x4 a1 = *(const f32x4*)(aprow + j0 + 4);
    unsigned long long b0 = __ballot(a0.x > 0.f);
    unsigned long long b1 = __ballot(a0.y > 0.f);
    unsigned long long b2 = __ballot(a0.z > 0.f);
    unsigned long long b3 = __ballot(a0.w > 0.f);
    unsigned long long b4 = __ballot(a1.x > 0.f);
    unsigned long long b5 = __ballot(a1.y > 0.f);
    unsigned long long b6 = __ballot(a1.z > 0.f);
    unsigned long long b7 = __ballot(a1.w > 0.f);
    if (lane == 0) {
      u64x2* mp = (u64x2*)(Mw + (((size_t)(i0 >> 4)) * 256 + jb) * 8);
      u64x2 v0; v0.x = b0; v0.y = b1;
      u64x2 v1; v1.x = b2; v1.y = b3;
      u64x2 v2; v2.x = b4; v2.y = b5;
      u64x2 v3; v3.x = b6; v3.y = b7;
      mp[0] = v0; mp[1] = v1; mp[2] = v2; mp[3] = v3;
    }
    f32x4 g0 = *(const f32x4*)(g + j0 + cgrp);
    f32x4 g1 = *(const f32x4*)(g + j0 + cgrp + 4);
    if (a0.x > 0.f) gmx = fmaxf(gmx, g0.x);
    if (a0.y > 0.f) gmx = fmaxf(gmx, g0.y);
    if (a0.z > 0.f) gmx = fmaxf(gmx, g0.z);
    if (a0.w > 0.f) gmx = fmaxf(gmx, g0.w);
    if (a1.x > 0.f) gmx = fmaxf(gmx, g1.x);
    if (a1.y > 0.f) gmx = fmaxf(gmx, g1.y);
    if (a1.z > 0.f) gmx = fmaxf(gmx, g1.z);
    if (a1.w > 0.f) gmx = fmaxf(gmx, g1.w);
    s16x8 af;
    af[0] = (short)f2bf(a0.x); af[1] = (short)f2bf(a0.y);
    af[2] = (short)f2bf(a0.z); af[3] = (short)f2bf(a0.w);
    af[4] = (short)f2bf(a1.x); af[5] = (short)f2bf(a1.y);
    af[6] = (short)f2bf(a1.z); af[7] = (short)f2bf(a1.w);
    const size_t bi = ((size_t)jb << 8) + lane;   // jb*4*64 + lane
    acc0 = __builtin_amdgcn_mfma_f32_16x16x32_bf16(af, Bv[bi      ], acc0, 0, 0, 0);
    acc1 = __builtin_amdgcn_mfma_f32_16x16x32_bf16(af, Bv[bi +  64], acc1, 0, 0, 0);
    acc2 = __builtin_amdgcn_mfma_f32_16x16x32_bf16(af, Bv[bi + 128], acc2, 0, 0, 0);
    acc3 = __builtin_amdgcn_mfma_f32_16x16x32_bf16(af, Bv[bi + 192], acc3, 0, 0, 0);
  }
  gmx = fmaxf(gmx, __shfl_xor(gmx, 16));
  gmx = fmaxf(gmx, __shfl_xor(gmx, 32));
  if (lane < 16) gred[w][lane] = gmx;
#pragma unroll
  for (int q = 0; q < 4; ++q) {
    red[w][lane][q] = acc0[q];
    red[w][lane][4 + q] = acc1[q];
    red[w][lane][8 + q] = acc2[q];
    red[w][lane][12 + q] = acc3[q];
  }
  __syncthreads();
  const int l = threadIdx.x & 63;
  const int b = (threadIdx.x >> 6) & 3;
  const int rh = threadIdx.x >> 8;
#pragma unroll
  for (int q = 0; q < 2; ++q) {
    const int reg = rh * 2 + q;
    float s = 0.f;
#pragma unroll
    for (int w8 = 0; w8 < 8; ++w8) s += red[w8][l][b * 4 + reg];
    const int row = ((l >> 4) << 2) + reg;
    U[(size_t)(i0 + row) * 64 + b * 16 + (l & 15)] = s;
  }
  if (threadIdx.x < 16) {
    float gm = -INFINITY;
#pragma unroll
    for (int w8 = 0; w8 < 8; ++w8) gm = fmaxf(gm, gred[w8][threadIdx.x]);
    Gmax[i0 + threadIdx.x] = gm;
  }
}

// ---------------- k2b: U f32 -> Upack bf16 (B-fragment layout) ----------------
__global__ __launch_bounds__(256) void k2b(const float* __restrict__ U,
                                           unsigned short* __restrict__ Upack) {
  const int w8 = blockIdx.x * 256 + threadIdx.x;   // 65536 groups of 8
  const int lp = w8 & 63;
  const int b = (w8 >> 6) & 3;
  const int kb = w8 >> 8;
  const int n = b * 16 + (lp & 15);
  const int k0 = kb * 32 + ((lp >> 4) << 3);
  s16x8 v;
#pragma unroll
  for (int e = 0; e < 8; ++e) v[e] = (short)f2bf(U[(size_t)(k0 + e) * 64 + n]);
  ((s16x8*)Upack)[w8] = v;
}

// ---------------- k3: fused softmax + attention@U + ELU ----------------
__global__ __launch_bounds__(512, 4) void k3(const unsigned long long* __restrict__ Mw,
                                             const unsigned short* __restrict__ Upack,
                                             const float* __restrict__ f,
                                             const float* __restrict__ g,
                                             const float* __restrict__ Gmax,
                                             float* __restrict__ out) {
  __shared__ float red[8][64][16];   // 32 KB
  __shared__ float wred[8][16];
  const int lane = threadIdx.x & 63;
  const int w = threadIdx.x >> 6;
  const int i0 = blockIdx.x << 4;
  const int r = lane & 15;
  const float fi = f[i0 + r];
  const float gmx = Gmax[i0 + r];
  float m = fi + gmx;
  m = fmaxf(m, 0.2f * m);                    // m_i = leaky(f_i + Gmax_i)
  const int cgrp = (lane >> 4) << 3;
  const s16x8* Uv = (const s16x8*)Upack;
  f32x4 acc0 = {0.f, 0.f, 0.f, 0.f};
  f32x4 acc1 = {0.f, 0.f, 0.f, 0.f};
  f32x4 acc2 = {0.f, 0.f, 0.f, 0.f};
  f32x4 acc3 = {0.f, 0.f, 0.f, 0.f};
  float wsum = 0.f;
  for (int t = 0; t < 32; ++t) {
    const int jb = w + (t << 3);
    const int j0 = jb << 5;
    const unsigned long long* mp = Mw + (((size_t)(i0 >> 4)) * 256 + jb) * 8;
    f32x4 g0 = *(const f32x4*)(g + j0 + cgrp);
    f32x4 g1 = *(const f32x4*)(g + j0 + cgrp + 4);
    s16x8 pf;
#pragma unroll
    for (int e = 0; e < 8; ++e) {
      const float gv = (e < 4) ? g0[e] : g1[e - 4];
      float ev = fi + gv;
      ev = fmaxf(ev, 0.2f * ev);             // LeakyReLU
      float wt = __expf(ev - m);
      const bool edge = ((mp[e] >> lane) & 1ull) != 0ull;
      wt = edge ? wt : 0.f;
      wsum += wt;
      pf[e] = (short)f2bf(wt);
    }
    const size_t bi = ((size_t)jb << 8) + lane;
    acc0 = __builtin_amdgcn_mfma_f32_16x16x32_bf16(pf, Uv[bi      ], acc0, 0, 0, 0);
    acc1 = __builtin_amdgcn_mfma_f32_16x16x32_bf16(pf, Uv[bi +  64], acc1, 0, 0, 0);
    acc2 = __builtin_amdgcn_mfma_f32_16x16x32_bf16(pf, Uv[bi + 128], acc2, 0, 0, 0);
    acc3 = __builtin_amdgcn_mfma_f32_16x16x32_bf16(pf, Uv[bi + 192], acc3, 0, 0, 0);
  }
  wsum += __shfl_xor(wsum, 16);
  wsum += __shfl_xor(wsum, 32);
  if (lane < 16) wred[w][lane] = wsum;
#pragma unroll
  for (int q = 0; q < 4; ++q) {
    red[w][lane][q] = acc0[q];
    red[w][lane][4 + q] = acc1[q];
    red[w][lane][8 + q] = acc2[q];
    red[w][lane][12 + q] = acc3[q];
  }
  __syncthreads();
  const int l = threadIdx.x & 63;
  const int b = (threadIdx.x >> 6) & 3;
  const int rh = threadIdx.x >> 8;
#pragma unroll
  for (int q = 0; q < 2; ++q) {
    const int reg = rh * 2 + q;
    float s = 0.f;
#pragma unroll
    for (int w8 = 0; w8 < 8; ++w8) s += red[w8][l][b * 4 + reg];
    const int row = ((l >> 4) << 2) + reg;
    float den = 0.f;
#pragma unroll
    for (int w8 = 0; w8 < 8; ++w8) den += wred[w8][row];
    float v = s / den;
    v = (v > 0.f) ? v : (expf(v) - 1.f);     // ELU
    out[(size_t)(i0 + row) * 64 + b * 16 + (l & 15)] = v;
  }
}

extern "C" void kernel_launch(void* const* d_in, const int* in_sizes, int n_in,
                              void* d_out, int out_size, void* d_ws, size_t ws_size,
                              hipStream_t stream) {
  const float* h   = (const float*)d_in[0];
  const float* adj = (const float*)d_in[1];
  const float* W   = (const float*)d_in[2];
  const float* a   = (const float*)d_in[3];
  float* out = (float*)d_out;
  char* ws = (char*)d_ws;
  // ws layout (13 MB total)
  unsigned short* Bpack = (unsigned short*)(ws);                         // 1 MB
  unsigned short* Upack = (unsigned short*)(ws + (1u << 20));            // 1 MB
  float* U    = (float*)(ws + (2u << 20));                               // 2 MB
  float* f    = (float*)(ws + (4u << 20));                               // 32 KB
  float* g    = (float*)(ws + (4u << 20) + 32768u);                      // 32 KB
  float* Gmax = (float*)(ws + (4u << 20) + 65536u);                      // 32 KB
  unsigned long long* Mw = (unsigned long long*)(ws + (5u << 20));       // 8 MB

  hipLaunchKernelGGL(k1, dim3(2048), dim3(256), 0, stream, h, W, a, Bpack, f, g);
  hipLaunchKernelGGL(k2, dim3(512), dim3(512), 0, stream, adj, Bpack, g, U, Mw, Gmax);
  hipLaunchKernelGGL(k2b, dim3(256), dim3(256), 0, stream, U, Upack);
  hipLaunchKernelGGL(k3, dim3(512), dim3(512), 0, stream, Mw, Upack, f, g, Gmax, out);
}